// Round 11
// baseline (431.370 us; speedup 1.0000x reference)
//
#include <hip/hip_runtime.h>
#include <hip/hip_bf16.h>

// 3-layer tanh RNN. B=32, T=64, D_IN=10000, H=200, N_CLASSES=2.
//
// R18:
//  * MFMA RECURRENCE: scalar rec step = ~1550cy (80 FMA/thread VALU-issue
//    + AGPR reads + 2 barriers). Replaced with MFMA engine: per step
//    h@Whh^T as M=16(row-broadcast: all A rows = h -> every C row = result),
//    N=13 tiles, K=7 chunks, 3-term split-bf16 => 42 MFMA/wave ~ 210cy +
//    14 ds_read_b128 A-frags + tanh epilogue + 2 bar_lds ~= 700cy/step.
//    Whh fragments (112 VGPR/lane) are MFMA operands -> AGPR-direct if
//    demoted (R17 discovery: fast rec variants lived in AGPRs all along).
//    Whh packed with the SAME frag-order pack as W_ih (proven layout).
//  * reduce_parts folded into chain L0 staging (new function anyway).
//    3 launches total: pack_all, gemm_l0, rnn_chain.
//  * gemm_l0 / gemm_job: R13/R17-proven versions unchanged.
//  * split-bf16 3-term everywhere: ~fp32 accuracy at bf16 MFMA rate.

typedef __bf16  bf16x8 __attribute__((ext_vector_type(8)));
typedef __bf16  bf16x4 __attribute__((ext_vector_type(4)));
typedef float   f32x4  __attribute__((ext_vector_type(4)));

#define HDIM 200
#define BM 64
#define CHUNK_B 26624   // bytes per packed k-chunk: hi 13 tiles x 1KB, lo same
#define MFMA(a, b, c) __builtin_amdgcn_mfma_f32_16x16x32_bf16(a, b, c, 0, 0, 0)

__device__ __forceinline__ void glds16(const void* g, void* l) {
    __builtin_amdgcn_global_load_lds(
        (const __attribute__((address_space(1))) unsigned int*)g,
        (__attribute__((address_space(3))) unsigned int*)l, 16, 0, 0);
}

__device__ __forceinline__ float fast_tanh(float x) {
    float e = __expf(-2.f * fabsf(x));
    float r = (1.f - e) / (1.f + e);
    return copysignf(r, x);
}

// LDS-only barrier: waits LDS ops, NOT in-flight global stores (no vmcnt).
__device__ __forceinline__ void bar_lds() {
    asm volatile("s_waitcnt lgkmcnt(0)" ::: "memory");
    __builtin_amdgcn_s_barrier();
}

// ---- pack [HDIM x K] fp32 -> chunks in FRAGMENT ORDER (R14-proven).
// Now packs 6 matrices: W_ih0/1/2 and W_hh0/1/2. ----
__global__ void pack_all(const float* __restrict__ Wi0,
                         const float* __restrict__ Wi1,
                         const float* __restrict__ Wi2,
                         const float* __restrict__ Wh0,
                         const float* __restrict__ Wh1,
                         const float* __restrict__ Wh2,
                         __bf16* __restrict__ Oi0,
                         __bf16* __restrict__ Oi1,
                         __bf16* __restrict__ Oi2,
                         __bf16* __restrict__ Oh0,
                         __bf16* __restrict__ Oh1,
                         __bf16* __restrict__ Oh2)
{
    const int T0 = 320 * 1664, TS = 7 * 1664;   // W_ih0; all others 7 chunks
    const int total = T0 + 5 * TS;
    for (int gt = blockIdx.x * blockDim.x + threadIdx.x; gt < total;
         gt += gridDim.x * blockDim.x) {
        const float* W; __bf16* out; int K, g;
        if (gt < T0)               { W = Wi0; out = Oi0; K = 10000; g = gt; }
        else {
            int r5 = gt - T0;
            int which = r5 / TS;   g = r5 - which * TS;  K = HDIM;
            switch (which) {
                case 0: W = Wi1; out = Oi1; break;
                case 1: W = Wi2; out = Oi2; break;
                case 2: W = Wh0; out = Oh0; break;
                case 3: W = Wh1; out = Oh1; break;
                default: W = Wh2; out = Oh2; break;
            }
        }

        const int kc = g / 1664;
        const int u  = g - kc * 1664;
        const int isLo = (u >= 832);
        const int u2 = isLo ? u - 832 : u;
        const int nt = u2 >> 6;              // n-tile 0..12
        const int l  = u2 & 63;              // lane slot
        const int r  = nt * 16 + (l & 15);   // 0..207
        const int k  = kc * 32 + (l >> 4) * 8;
        bf16x8 v;
        if (r < HDIM && k < K) {             // K % 8 == 0
            const float* p = W + (size_t)r * K + k;
            float4 a = *(const float4*)p, b = *(const float4*)(p + 4);
            float f[8] = {a.x, a.y, a.z, a.w, b.x, b.y, b.z, b.w};
#pragma unroll
            for (int i = 0; i < 8; ++i) {
                __bf16 h = (__bf16)f[i];
                v[i] = isLo ? (__bf16)(f[i] - (float)h) : h;
            }
        } else {
#pragma unroll
            for (int i = 0; i < 8; ++i) v[i] = (__bf16)0.f;
        }
        *(bf16x8*)&out[(size_t)g * 8] = v;
    }
}

// ---- one GEMM tile-job (R14-exact body). Ab: 2x4096 bf16, Bb: 2x13312. ----
__device__ __noinline__ void gemm_job(
    const float* __restrict__ A, int lda, int K,
    const __bf16* __restrict__ Bpack, float* __restrict__ C,
    int ksteps, int kc0, int m0,
    __bf16* Ab, __bf16* Bb, int tid)
{
    const int wv = tid >> 6, lane = tid & 63;
    const int r16 = lane & 15, kg = lane >> 4;
    const int mg = wv & 1, ng = wv >> 1;
    const int nt0 = ng ? 1 + ng * 3 : 0;        // 0,4,7,10
    const int ntw = ng ? 3 : 4;
    const int fb  = lane * 8;                   // lane's fragment offset (bf16)

    const int a_row = tid >> 3;          // 0..63
    const int a_q   = tid & 7;           // float4 column group
    const float* Arow = A + (size_t)(m0 + a_row) * lda + a_q * 4;
    const int a_off = (a_row >> 4) * 512 + ((a_row & 15) + 16 * (a_q >> 1)) * 8
                    + (a_q & 1) * 4;

    f32x4 acc[2][4];
#pragma unroll
    for (int mi = 0; mi < 2; ++mi)
#pragma unroll
        for (int j = 0; j < 4; ++j) acc[mi][j] = (f32x4)0.f;

    float av[4];
    auto loadA = [&](int ks) {
        const int kb = (kc0 + ks) * 32;
        if (kb + a_q * 4 < K) {          // 4-granular, K % 4 == 0
            float4 x0 = *(const float4*)(Arow + kb);
            av[0] = x0.x; av[1] = x0.y; av[2] = x0.z; av[3] = x0.w;
        } else {
#pragma unroll
            for (int i = 0; i < 4; ++i) av[i] = 0.f;
        }
    };
    auto issueB = [&](int ks, int buf) {
        const char* src = (const char*)Bpack + (size_t)(kc0 + ks) * CHUNK_B;
        char* dst = (char*)Bb + (size_t)buf * CHUNK_B;
#pragma unroll
        for (int r = 0; r < 3; ++r)
            glds16(src + (r * 512 + tid) * 16, dst + (r * 512 + tid) * 16);
        if (tid < 128)
            glds16(src + (1536 + tid) * 16, dst + (1536 + tid) * 16);
    };

    loadA(0);
    issueB(0, 0);

    for (int ks = 0; ks < ksteps; ++ks) {
        const int cur = ks & 1, nxt = cur ^ 1;
        bf16x4 th, tl;
#pragma unroll
        for (int i = 0; i < 4; ++i) {
            __bf16 h = (__bf16)av[i];
            th[i] = h; tl[i] = (__bf16)(av[i] - (float)h);
        }
        *(bf16x4*)&Ab[cur * 4096 + a_off]        = th;
        *(bf16x4*)&Ab[cur * 4096 + 2048 + a_off] = tl;
        __syncthreads();   // drains glds B(ks) + A writes (vmcnt+lgkm)
        if (ks + 1 < ksteps) { issueB(ks + 1, nxt); loadA(ks + 1); }

        const int ao0 = (mg * 2 + 0) * 512 + fb;
        const int ao1 = (mg * 2 + 1) * 512 + fb;
        bf16x8 ah0 = *(const bf16x8*)&Ab[cur * 4096 + ao0];
        bf16x8 al0 = *(const bf16x8*)&Ab[cur * 4096 + 2048 + ao0];
        bf16x8 ah1 = *(const bf16x8*)&Ab[cur * 4096 + ao1];
        bf16x8 al1 = *(const bf16x8*)&Ab[cur * 4096 + 2048 + ao1];
#pragma unroll
        for (int j = 0; j < 4; ++j) {
            if (j < ntw) {
                const int bo = (nt0 + j) * 512 + fb;
                bf16x8 bh = *(const bf16x8*)&Bb[cur * 13312 + bo];
                bf16x8 bl = *(const bf16x8*)&Bb[cur * 13312 + 6656 + bo];
                acc[0][j] = MFMA(al0, bh, acc[0][j]);
                acc[0][j] = MFMA(ah0, bl, acc[0][j]);
                acc[0][j] = MFMA(ah0, bh, acc[0][j]);
                acc[1][j] = MFMA(al1, bh, acc[1][j]);
                acc[1][j] = MFMA(ah1, bl, acc[1][j]);
                acc[1][j] = MFMA(ah1, bh, acc[1][j]);
            }
        }
    }

    // epilogue: C/D layout col=lane&15, row=(lane>>4)*4+reg
#pragma unroll
    for (int mi = 0; mi < 2; ++mi) {
        const int rb = m0 + mg * 32 + mi * 16 + kg * 4;
#pragma unroll
        for (int j = 0; j < 4; ++j) {
            if (j < ntw) {
                const int n = (nt0 + j) * 16 + r16;
                if (n < HDIM)
#pragma unroll
                    for (int r = 0; r < 4; ++r)
                        C[(size_t)(rb + r) * HDIM + n] = acc[mi][j][r];
            }
        }
    }
    __syncthreads();   // drains loads/stores; LDS safe for next phase
}

// ---- L0 GEMM wrapper: grid (32 m-blocks, 16 k-splits) ----
__global__ __launch_bounds__(512, 4)
void gemm_l0(const float* __restrict__ x, const __bf16* __restrict__ W0p,
             float* __restrict__ Ppart, int per_split)
{
    __shared__ alignas(16) char U[69632];
    gemm_job(x, 10000, 10000, W0p,
             Ppart + (size_t)blockIdx.y * per_split,
             20, blockIdx.y * 20, blockIdx.x * BM,
             (__bf16*)U, (__bf16*)(U + 16384), threadIdx.x);
}

// ---- per-batch chain: [sum partials ->] rec0 -> gemm1 -> rec1 -> gemm2
//      -> rec2 -> fc. 32 blocks, 1 per batch. MFMA recurrence. ----
__global__ __launch_bounds__(512, 1)
void rnn_chain(const float* __restrict__ Ppart, int nparts, int pstride,
               float* P, float* Hbuf,
               const __bf16* __restrict__ Wh0p, const float* __restrict__ bih0,
               const float* __restrict__ bhh0,
               const __bf16* __restrict__ Wh1p, const float* __restrict__ bih1,
               const float* __restrict__ bhh1,
               const __bf16* __restrict__ Wh2p, const float* __restrict__ bih2,
               const float* __restrict__ bhh2,
               const __bf16* __restrict__ W1p, const __bf16* __restrict__ W2p,
               const float* __restrict__ fcw, const float* __restrict__ fcb,
               float* __restrict__ outp)
{
    const int b   = blockIdx.x;
    const int tid = threadIdx.x;

    __shared__ alignas(16) char U[69632];     // union: gemm Ab+Bb | rec bufs
    __bf16* Ab   = (__bf16*)U;
    __bf16* Bb   = (__bf16*)(U + 16384);
    float*  preS = (float*)U;                 // 12800 f
    float*  bias = (float*)(U + 51200);       // 200 f
    float*  hF   = (float*)(U + 52000);       // 200 f (fp32 h for fc head)
    __bf16* hSh  = (__bf16*)(U + 52800);      // 224 bf16 (hi plane, padded)
    __bf16* hSl  = (__bf16*)(U + 53264);      // 224 bf16 (lo plane)

    const int wv = tid >> 6, lane = tid & 63;
    const int kg = lane >> 4;                 // A-frag k-subgroup
    const int ntA = wv;                       // n-tiles owned: wv and wv+8
    const int ntB = wv + 8;

    // MFMA recurrence: h_{t+1} = tanh(pre_t + h_t @ Whh^T).
    // A-operand row-broadcast: every lane supplies h[k] for its k-slot
    // regardless of row -> all 16 C rows equal the result; reg0/lanes0-15
    // extract it. Whh fragments resident across the 64-step loop.
    auto recM = [&](const float* preG, int np, int pstr,
                    const __bf16* WhhP, const float* bih, const float* bhh,
                    float* Hout) {
        {   // stage pre slab, summing np k-split partials (coalesced)
            const float4* ps = (const float4*)(preG + (size_t)b * 64 * HDIM);
            float4* pd = (float4*)preS;
            const size_t pq = (size_t)pstr / 4;
            for (int i = tid; i < 3200; i += 512) {
                float4 s = ps[i];
                for (int r = 1; r < np; ++r) {
                    float4 v = ps[(size_t)r * pq + i];
                    s.x += v.x; s.y += v.y; s.z += v.z; s.w += v.w;
                }
                pd[i] = s;
            }
        }
        if (tid < HDIM) bias[tid] = bih[tid] + bhh[tid];
        if (tid < 224) { hSh[tid] = (__bf16)0.f; hSl[tid] = (__bf16)0.f; }

        // resident Whh B-fragments: [nt][kc][hi/lo], frag = chunk[kc] at
        // (isLo?832:0 units) + (nt*64+lane)*16B  (identical to gemm's Bb).
        bf16x8 wA[7][2], wB[7][2];
#pragma unroll
        for (int kc = 0; kc < 7; ++kc) {
            const __bf16* s0 = WhhP + (size_t)kc * 13312 + ((size_t)ntA * 64 + lane) * 8;
            wA[kc][0] = *(const bf16x8*)s0;
            wA[kc][1] = *(const bf16x8*)(s0 + 6656);
            if (ntB < 13) {
                const __bf16* s1 = WhhP + (size_t)kc * 13312 + ((size_t)ntB * 64 + lane) * 8;
                wB[kc][0] = *(const bf16x8*)s1;
                wB[kc][1] = *(const bf16x8*)(s1 + 6656);
            } else {
#pragma unroll
                for (int i = 0; i < 8; ++i) { wB[kc][0][i] = (__bf16)0.f; wB[kc][1][i] = (__bf16)0.f; }
            }
        }
        __syncthreads();

        for (int t = 0; t < 64; ++t) {
            // A-fragments: lane supplies h[kc*32 + kg*8 + i] (row-broadcast)
            bf16x8 hh[7], hl[7];
#pragma unroll
            for (int kc = 0; kc < 7; ++kc) {
                hh[kc] = *(const bf16x8*)&hSh[kc * 32 + kg * 8];
                hl[kc] = *(const bf16x8*)&hSl[kc * 32 + kg * 8];
            }
            f32x4 aA = (f32x4)0.f, aB = (f32x4)0.f;
#pragma unroll
            for (int kc = 0; kc < 7; ++kc) {
                aA = MFMA(hl[kc], wA[kc][0], aA);
                aA = MFMA(hh[kc], wA[kc][1], aA);
                aA = MFMA(hh[kc], wA[kc][0], aA);
                aB = MFMA(hl[kc], wB[kc][0], aB);
                aB = MFMA(hh[kc], wB[kc][1], aB);
                aB = MFMA(hh[kc], wB[kc][0], aB);
            }
            bar_lds();   // all waves' A-frag reads done -> hS safe to rewrite
            if (lane < 16) {
                {   // ntA tile: n = ntA*16+lane, always < 128 < 200
                    const int n = ntA * 16 + lane;
                    float v = fast_tanh(aA[0] + preS[t * HDIM + n] + bias[n]);
                    __bf16 vh = (__bf16)v;
                    hSh[n] = vh; hSl[n] = (__bf16)(v - (float)vh);
                    hF[n] = v;
                    Hout[((size_t)b * 64 + t) * HDIM + n] = v;
                }
                const int n = ntB * 16 + lane;
                if (n < HDIM) {
                    float v = fast_tanh(aB[0] + preS[t * HDIM + n] + bias[n]);
                    __bf16 vh = (__bf16)v;
                    hSh[n] = vh; hSl[n] = (__bf16)(v - (float)vh);
                    hF[n] = v;
                    Hout[((size_t)b * 64 + t) * HDIM + n] = v;
                }
            }
            bar_lds();   // h(t+1) visible for next step's A-frag reads
        }
    };

    float* Hslab = Hbuf + (size_t)b * 64 * HDIM;
    float* Pslab = P + (size_t)b * 64 * HDIM;

    recM(Ppart, nparts, pstride, Wh0p, bih0, bhh0, Hbuf);
    __syncthreads();                          // drain Hout stores before gemm reads
    gemm_job(Hslab, HDIM, HDIM, W1p, Pslab, 7, 0, 0, Ab, Bb, tid);

    recM(P, 1, 0, Wh1p, bih1, bhh1, Hbuf);
    __syncthreads();
    gemm_job(Hslab, HDIM, HDIM, W2p, Pslab, 7, 0, 0, Ab, Bb, tid);

    recM(P, 1, 0, Wh2p, bih2, bhh2, Hbuf);

    // fc head: hF holds fp32 h_63 (last bar_lds made it visible)
    if (tid < 16) {
        const int cls = tid & 1, sl = tid >> 1;      // 8 slices of 25
        const float* fw = fcw + cls * HDIM + sl * 25;
        const float* hp = hF + sl * 25;
        float sacc = 0.f;
#pragma unroll
        for (int j = 0; j < 25; ++j) sacc += hp[j] * fw[j];
        sacc += __shfl_xor(sacc, 2);
        sacc += __shfl_xor(sacc, 4);
        sacc += __shfl_xor(sacc, 8);
        if (sl == 0) outp[b * 2 + cls] = sacc + fcb[cls];
    }
}

extern "C" void kernel_launch(void* const* d_in, const int* in_sizes, int n_in,
                              void* d_out, int out_size, void* d_ws, size_t ws_size,
                              hipStream_t stream) {
    const float* x     = (const float*)d_in[0];
    const float* W_ih0 = (const float*)d_in[1];
    const float* W_hh0 = (const float*)d_in[2];
    const float* b_ih0 = (const float*)d_in[3];
    const float* b_hh0 = (const float*)d_in[4];
    const float* W_ih1 = (const float*)d_in[5];
    const float* W_hh1 = (const float*)d_in[6];
    const float* b_ih1 = (const float*)d_in[7];
    const float* b_hh1 = (const float*)d_in[8];
    const float* W_ih2 = (const float*)d_in[9];
    const float* W_hh2 = (const float*)d_in[10];
    const float* b_ih2 = (const float*)d_in[11];
    const float* b_hh2 = (const float*)d_in[12];
    const float* fc_w  = (const float*)d_in[13];
    const float* fc_b  = (const float*)d_in[14];
    float* out = (float*)d_out;

    const size_t PE = (size_t)2048 * HDIM;          // 409600
    const size_t CH = (size_t)7 * 13312;            // small pack size (bf16)
    float* P     = (float*)d_ws;
    float* Hbuf  = P + PE;
    float* Ppart = Hbuf + PE;                       // 16 x 409600
    __bf16* W0p  = (__bf16*)(Ppart + 16 * PE);      // 320 chunks
    __bf16* W1p  = W0p + (size_t)320 * 13312;
    __bf16* W2p  = W1p + CH;
    __bf16* Wh0p = W2p + CH;
    __bf16* Wh1p = Wh0p + CH;
    __bf16* Wh2p = Wh1p + CH;
    // total ws: ~39 MB

    // ---- 3 launches total ----
    pack_all<<<1024, 256, 0, stream>>>(W_ih0, W_ih1, W_ih2,
                                       W_hh0, W_hh1, W_hh2,
                                       W0p, W1p, W2p, Wh0p, Wh1p, Wh2p);
    gemm_l0<<<dim3(32, 16), 512, 0, stream>>>(x, W0p, Ppart, (int)PE);
    rnn_chain<<<32, 512, 0, stream>>>(Ppart, 16, (int)PE, P, Hbuf,
                                      Wh0p, b_ih0, b_hh0,
                                      Wh1p, b_ih1, b_hh1,
                                      Wh2p, b_ih2, b_hh2,
                                      W1p, W2p, fc_w, fc_b, out);
}